// Round 6
// baseline (80.256 us; speedup 1.0000x reference)
//
#include <hip/hip_runtime.h>
#include <hip/hip_bf16.h>

#define INF_VAL 100000000.0f
#define RADIUS 1.5f
#define NUM_CLASSES 80
#define G_BOXES 50

// Two locations per thread: thread t of a 128-thread block handles locations
// base+t and base+t+128 (base = blockIdx.x*256). Per-box data (uniform VMEM
// broadcast box4[g] + one ds_read_b128 sder[g]) is loaded ONCE and reused for
// both locations -> per-iteration memory-op issue halved vs round 4, VALU
// unchanged. All loads/stores remain perfectly lane-coalesced.
//
// Per-location math is verbatim the round-4 kernel (measured absmax 0.0):
//  - cx,cy,area precomputed with the reference's exact formulas.
//  - in_radius via the exact comparison equivalence (x>cx-rad)&(l>0) etc.
//  - max_reg identical; area compared pre-rounded; strict < argmin keeps
//    first-min tie-break; /stride as exact power-of-two reciprocal mul.
__global__ void __launch_bounds__(128) fcos_assign_kernel(
    const float* __restrict__ locations,    // [L,2]
    const float* __restrict__ stride_loc,   // [L]
    const float* __restrict__ size_ranges,  // [L,2]
    const float* __restrict__ gt_boxes,     // [B,G,4]
    const int*   __restrict__ gt_classes,   // [B,G]
    float* __restrict__ out,                // labels[B*L] ++ reg[B*L*4] ++ ctr[B*L]
    int L, int B)
{
    const int b    = blockIdx.y;
    const int base = blockIdx.x * 256;
    const int i0   = base + threadIdx.x;
    const int i1   = i0 + 128;

    __shared__ float4 sder[G_BOXES];   // {cx, cy, area, classf}

    const float4* __restrict__ box4 =
        reinterpret_cast<const float4*>(gt_boxes) + (size_t)b * G_BOXES;

    if (threadIdx.x < G_BOXES) {
        const int g = threadIdx.x;
        const float4 bx = box4[g];
        float4 v;
        v.x = (bx.x + bx.z) * 0.5f;            // cx  (ref rounding)
        v.y = (bx.y + bx.w) * 0.5f;            // cy
        v.z = (bx.z - bx.x) * (bx.w - bx.y);   // area
        v.w = (float)gt_classes[(size_t)b * G_BOXES + g];
        sder[g] = v;
    }
    __syncthreads();

    if (i0 >= L) return;
    const bool have1 = (i1 < L);

    // location 0 state
    const float2 xy0 = *reinterpret_cast<const float2*>(locations + 2 * (size_t)i0);
    const float  x0 = xy0.x, y0 = xy0.y;
    const float  st0 = stride_loc[i0];
    const float2 sr0 = *reinterpret_cast<const float2*>(size_ranges + 2 * (size_t)i0);
    const float  lo0 = sr0.x, hi0 = sr0.y;
    const float  rad0 = st0 * RADIUS;

    // location 1 state (dup loc0 when OOB; stores guarded)
    float x1 = x0, y1 = y0, st1 = st0, lo1 = lo0, hi1 = hi0, rad1 = rad0;
    if (have1) {
        const float2 xy1 = *reinterpret_cast<const float2*>(locations + 2 * (size_t)i1);
        x1 = xy1.x; y1 = xy1.y;
        st1 = stride_loc[i1];
        const float2 sr1 = *reinterpret_cast<const float2*>(size_ranges + 2 * (size_t)i1);
        lo1 = sr1.x; hi1 = sr1.y;
        rad1 = st1 * RADIUS;
    }

    float bestA0 = INF_VAL, bestA1 = INF_VAL;
    int   bestG0 = 0,       bestG1 = 0;

    #pragma unroll 5
    for (int g = 0; g < G_BOXES; ++g) {
        const float4 bx = box4[g];   // uniform addr -> one VMEM broadcast, L1-hot
        const float4 d  = sder[g];   // one ds_read_b128, shared by both locations

        // ---- location 0 ----
        {
            const float l  = x0 - bx.x;
            const float t  = y0 - bx.y;
            const float r  = bx.z - x0;
            const float bt = bx.w - y0;
            const float c0 = d.x - rad0, c1 = d.x + rad0;
            const float c2 = d.y - rad0, c3 = d.y + rad0;
            const bool in_radius =
                (x0 > c0) & (x0 < c1) & (y0 > c2) & (y0 < c3) &
                (fminf(fminf(l, t), fminf(r, bt)) > 0.0f);
            const float max_reg = fminf(fmaxf(l, r), fmaxf(t, bt));
            const bool cared = (max_reg >= lo0) & (max_reg <= hi0);
            const float val = (in_radius & cared) ? d.z : INF_VAL;
            if (val < bestA0) { bestA0 = val; bestG0 = g; }
        }
        // ---- location 1 ----
        {
            const float l  = x1 - bx.x;
            const float t  = y1 - bx.y;
            const float r  = bx.z - x1;
            const float bt = bx.w - y1;
            const float c0 = d.x - rad1, c1 = d.x + rad1;
            const float c2 = d.y - rad1, c3 = d.y + rad1;
            const bool in_radius =
                (x1 > c0) & (x1 < c1) & (y1 > c2) & (y1 < c3) &
                (fminf(fminf(l, t), fminf(r, bt)) > 0.0f);
            const float max_reg = fminf(fmaxf(l, r), fmaxf(t, bt));
            const bool cared = (max_reg >= lo1) & (max_reg <= hi1);
            const float val = (in_radius & cared) ? d.z : INF_VAL;
            if (val < bestA1) { bestA1 = val; bestG1 = g; }
        }
    }

    const size_t BL = (size_t)B * L;

    // ---- epilogue location 0 ----
    {
        const float4 bb = box4[bestG0];             // divergent L1 gather (800 B hot)
        const float inv_s = 1.0f / st0;             // pow2 -> exact
        const float rl = (x0 - bb.x) * inv_s;
        const float rt = (y0 - bb.y) * inv_s;
        const float rr = (bb.z - x0) * inv_s;
        const float rb = (bb.w - y0) * inv_s;
        const float clsf = reinterpret_cast<const float*>(sder)[bestG0 * 4 + 3];
        const float label = (bestA0 >= INF_VAL) ? (float)NUM_CLASSES : clsf;
        const float lr0 = rl + 1e-5f, lr1 = rr + 1e-5f;
        const float tb0 = rt + 1e-5f, tb1 = rb + 1e-5f;
        float ctr = (fminf(lr0, lr1) / fmaxf(lr0, lr1)) * (fminf(tb0, tb1) / fmaxf(tb0, tb1));
        ctr = sqrtf(fmaxf(ctr, 0.0f));

        const size_t bl = (size_t)b * L + i0;
        out[bl] = label;
        float4 rg; rg.x = rl; rg.y = rt; rg.z = rr; rg.w = rb;
        *reinterpret_cast<float4*>(out + BL + bl * 4) = rg;
        out[5 * BL + bl] = ctr;
    }

    // ---- epilogue location 1 ----
    if (have1) {
        const float4 bb = box4[bestG1];
        const float inv_s = 1.0f / st1;
        const float rl = (x1 - bb.x) * inv_s;
        const float rt = (y1 - bb.y) * inv_s;
        const float rr = (bb.z - x1) * inv_s;
        const float rb = (bb.w - y1) * inv_s;
        const float clsf = reinterpret_cast<const float*>(sder)[bestG1 * 4 + 3];
        const float label = (bestA1 >= INF_VAL) ? (float)NUM_CLASSES : clsf;
        const float lr0 = rl + 1e-5f, lr1 = rr + 1e-5f;
        const float tb0 = rt + 1e-5f, tb1 = rb + 1e-5f;
        float ctr = (fminf(lr0, lr1) / fmaxf(lr0, lr1)) * (fminf(tb0, tb1) / fmaxf(tb0, tb1));
        ctr = sqrtf(fmaxf(ctr, 0.0f));

        const size_t bl = (size_t)b * L + i1;
        out[bl] = label;
        float4 rg; rg.x = rl; rg.y = rt; rg.z = rr; rg.w = rb;
        *reinterpret_cast<float4*>(out + BL + bl * 4) = rg;
        out[5 * BL + bl] = ctr;
    }
}

extern "C" void kernel_launch(void* const* d_in, const int* in_sizes, int n_in,
                              void* d_out, int out_size, void* d_ws, size_t ws_size,
                              hipStream_t stream) {
    const float* locations   = (const float*)d_in[0];
    const float* stride_loc  = (const float*)d_in[1];
    const float* size_ranges = (const float*)d_in[2];
    const float* gt_boxes    = (const float*)d_in[3];
    const int*   gt_classes  = (const int*)d_in[4];
    float* out = (float*)d_out;

    const int L = in_sizes[1];            // 20267
    const int B = in_sizes[4] / G_BOXES;  // 16

    dim3 block(128);
    dim3 grid((L + 255) / 256, B);        // each block covers 256 locations
    fcos_assign_kernel<<<grid, block, 0, stream>>>(
        locations, stride_loc, size_ranges, gt_boxes, gt_classes, out, L, B);
}